// Round 3
// baseline (265.438 us; speedup 1.0000x reference)
//
#include <hip/hip_runtime.h>
#include <hip/hip_bf16.h>
#include <stdint.h>

typedef __bf16 bf16_t;
typedef bf16_t bf16x8 __attribute__((ext_vector_type(8)));
typedef float f32x4 __attribute__((ext_vector_type(4)));

#define T_LEN 2048
#define C_LEN 2048
#define NB 128
#define TN 256
#define SROWS 2064   // 16 zero-halo rows + 2048 data rows per batch
#define XROWS 288    // 9 x 4KB GLL issues = 288 rows of 128B; 272 used

// async global->LDS, 16B per lane; LDS dest = wave-uniform base + lane*16
#define GLL(gp, lp) __builtin_amdgcn_global_load_lds( \
    (const __attribute__((address_space(1))) uint32_t*)(gp), \
    (__attribute__((address_space(3))) uint32_t*)(lp), 16, 0, 0)

// ---------------------------------------------------------------------------
// Prepack weights into per-lane MFMA A-fragment layout (verified r1/r2):
// wpk[blk][ks(32)][mt(4)][lane(64)][j(8)]
//   = bv[blk][o = mt*16 + (lane&15)][i = (ks&1)*32 + (lane>>4)*8 + j][k = ks>>1]
// ---------------------------------------------------------------------------
__global__ __launch_bounds__(256) void prepack_kernel(
    const float* __restrict__ bv, bf16_t* __restrict__ wpk)
{
  const int blk = blockIdx.x;
  const int mt  = blockIdx.y;
  const int tid = threadIdx.x;
  __shared__ float lw[16 * 64 * 17];

  const float* src = bv + (size_t)blk * 65536 + (size_t)mt * 16384;
  for (int p = 0; p < 16; ++p) {
    int idx = p * 1024 + tid * 4;
    const float4 v = *(const float4*)(src + idx);
    int o = idx >> 10;
    int i = (idx >> 4) & 63;
    int k = idx & 15;
    float* d = &lw[(o * 64 + i) * 17 + k];
    d[0] = v.x; d[1] = v.y; d[2] = v.z; d[3] = v.w;
  }
  __syncthreads();

  const int e0 = tid * 2;
  const int l  = e0 >> 3;
  const int j  = e0 & 7;
  const int o  = l & 15;
  for (int ks = 0; ks < 32; ++ks) {
    const int k  = ks >> 1;
    const int i0 = (ks & 1) * 32 + (l >> 4) * 8 + j;
    const float a = lw[(o * 64 + i0) * 17 + k];
    const float b = lw[(o * 64 + i0 + 1) * 17 + k];
    const uint16_t ba = __builtin_bit_cast(uint16_t, (bf16_t)a);
    const uint16_t bb = __builtin_bit_cast(uint16_t, (bf16_t)b);
    const uint32_t packed = (uint32_t)ba | ((uint32_t)bb << 16);
    const size_t off = ((((size_t)blk * 32 + ks) * 4 + mt) * 512) + e0;
    *(uint32_t*)(wpk + off) = packed;
  }
}

// ---------------------------------------------------------------------------
// Zero the halo rows of S.
// ---------------------------------------------------------------------------
__global__ __launch_bounds__(256) void padzero_kernel(bf16_t* __restrict__ S)
{
  const int p = blockIdx.x;  // 0..79
  const size_t g = (p < 64) ? ((size_t)(p >> 4) * SROWS + (p & 15))
                            : ((size_t)4 * SROWS + (p - 64));
  uint4 z = {0u, 0u, 0u, 0u};
  *(uint4*)(S + g * C_LEN + (size_t)threadIdx.x * 8) = z;
}

// ---------------------------------------------------------------------------
// x prepass: f32 [n][c][t] -> bf16 S[n][16+t][c'], c' = c ^ ((t&7)<<3)
// within each 64-ch block (XOR swizzle baked into global layout).
// ---------------------------------------------------------------------------
__global__ __launch_bounds__(256) void xprep_kernel(
    const float* __restrict__ x, bf16_t* __restrict__ S)
{
  const int tb = blockIdx.x, cb = blockIdx.y, n = blockIdx.z;
  const int tid = threadIdx.x;
  __shared__ float lt[64 * 67 + 4];

  #pragma unroll
  for (int p = 0; p < 4; ++p) {
    const int idx = p * 256 + tid;
    const int c   = idx >> 4;
    const int t4  = (idx & 15) * 4;
    const float4 v = *(const float4*)(
        x + ((size_t)n * C_LEN + cb * 64 + c) * T_LEN + tb * 64 + t4);
    float* d = &lt[c * 67 + t4];
    d[0] = v.x; d[1] = v.y; d[2] = v.z; d[3] = v.w;
  }
  __syncthreads();

  #pragma unroll
  for (int p = 0; p < 2; ++p) {
    const int idx = p * 256 + tid;
    const int tl  = idx >> 3;
    const int seg = idx & 7;
    const int t   = tb * 64 + tl;
    const int cbase = (seg * 8) ^ ((t & 7) << 3);
    uint32_t w[4];
    #pragma unroll
    for (int h = 0; h < 4; ++h) {
      const float a = lt[(cbase + 2 * h) * 67 + tl];
      const float b = lt[(cbase + 2 * h + 1) * 67 + tl];
      const uint16_t ba = __builtin_bit_cast(uint16_t, (bf16_t)a);
      const uint16_t bb = __builtin_bit_cast(uint16_t, (bf16_t)b);
      w[h] = (uint32_t)ba | ((uint32_t)bb << 16);
    }
    uint4 u4 = {w[0], w[1], w[2], w[3]};
    *(uint4*)(S + ((size_t)n * SROWS + 16 + t) * C_LEN + cb * 64 + seg * 8) = u4;
  }
}

// ---------------------------------------------------------------------------
// Main kernel. WG = (t-tile of 256, target row, batch).
// - A (weights) loaded global->VGPR straight from L2/L3-resident wpk
//   (already in fragment layout) -- never touches LDS.
// - x staged via global_load_lds into double-buffered xst; ONE
//   __syncthreads per block (its vmcnt(0)+lgkmcnt(0) drain is the fence).
// - Per-tr active block list built once via deterministic ballot prefix.
// ---------------------------------------------------------------------------
__global__ __launch_bounds__(256, 2) void bsconv_kernel(
    const bf16_t* __restrict__ S, const bf16_t* __restrict__ wpk,
    const int* __restrict__ cols, const int* __restrict__ rows,
    float* __restrict__ y)
{
  const int tt = blockIdx.x, tr = blockIdx.y, n = blockIdx.z;
  const int t0 = tt * TN;
  const int tid = threadIdx.x;
  const int lane = tid & 63, wv = tid >> 6;

  __shared__ __attribute__((aligned(16))) bf16_t xst[2][XROWS * 64]; // 73728 B
  __shared__ int alist[NB];
  __shared__ int clds[NB];
  __shared__ unsigned long long wmask[2];

  // ---- build active-block list (order-preserving => deterministic) ----
  {
    const int r = (tid < NB) ? rows[tid] : -1;
    if (tid < NB) clds[tid] = cols[tid];
    const bool match = (r == tr);
    const unsigned long long m = __ballot(match);
    if (wv < 2 && lane == 0) wmask[wv] = m;
    __syncthreads();
    if (match) {
      int pos = __popcll(wmask[wv] & ((1ull << lane) - 1ull));
      if (wv == 1) pos += __popcll(wmask[0]);
      alist[pos] = tid;
    }
    __syncthreads();
  }
  const int cnt = __popcll(wmask[0]) + __popcll(wmask[1]);

  f32x4 acc[4][4];
  #pragma unroll
  for (int a = 0; a < 4; ++a)
    #pragma unroll
    for (int b = 0; b < 4; ++b) {
      f32x4 z = {0.f, 0.f, 0.f, 0.f};
      acc[a][b] = z;
    }

  const size_t srow0 = (size_t)n * SROWS + t0;   // S row of LDS row u=0
  const int lxb = wv * 1024 + lane * 16;         // lane byte within 4KB issue

  auto issue_x = [&](int cb, int buf) {
    #pragma unroll
    for (int q = 0; q < 9; ++q) {
      const int lb = q * 4096 + lxb;
      const int u  = lb >> 7;
      const int ib = (lb >> 1) & 63;
      GLL(S + (srow0 + u) * C_LEN + cb * 64 + ib, (char*)xst[buf] + lb);
    }
  };

  if (cnt > 0) issue_x(clds[alist[0]], 0);

  for (int j = 0; j < cnt; ++j) {
    __syncthreads();              // drains vmcnt: xst[j&1] valid; buf j^1 free
    if (j + 1 < cnt) issue_x(clds[alist[j + 1]], (j + 1) & 1);

    const bf16_t* __restrict__ wb = wpk + (size_t)alist[j] * 65536;
    const bf16_t* xb = xst[j & 1];

    #pragma unroll 4
    for (int ks = 0; ks < 32; ++ks) {
      const int k  = ks >> 1;
      const int ih = (ks & 1) * 32;
      bf16x8 afr[4];
      #pragma unroll
      for (int mt = 0; mt < 4; ++mt)
        afr[mt] = *(const bf16x8*)(wb + (size_t)((ks * 4 + mt) * 64 + lane) * 8);
      const int ub   = wv * 64 + (lane & 15) + k + 1;
      const int scol = (ih + ((lane >> 4) & 3) * 8) ^ ((ub & 7) << 3);
      bf16x8 bfr[4];
      #pragma unroll
      for (int nt = 0; nt < 4; ++nt)
        bfr[nt] = *(const bf16x8*)(xb + (ub + nt * 16) * 64 + scol);
      #pragma unroll
      for (int mt = 0; mt < 4; ++mt)
        #pragma unroll
        for (int nt = 0; nt < 4; ++nt)
          acc[mt][nt] = __builtin_amdgcn_mfma_f32_16x16x32_bf16(
              afr[mt], bfr[nt], acc[mt][nt], 0, 0, 0);
    }
  }

  // ---- store (each output element exactly once; empty rows store zeros) ----
  const int mlo = ((lane >> 4) & 3) * 4, nn = lane & 15;
  #pragma unroll
  for (int mt = 0; mt < 4; ++mt) {
    #pragma unroll
    for (int nt = 0; nt < 4; ++nt) {
      const int t = t0 + wv * 64 + nt * 16 + nn;
      float* yp = y + ((size_t)n * C_LEN + (size_t)(tr * 64 + mt * 16 + mlo)) * T_LEN + t;
      #pragma unroll
      for (int r = 0; r < 4; ++r)
        yp[(size_t)r * T_LEN] = acc[mt][nt][r];
    }
  }
}

extern "C" void kernel_launch(void* const* d_in, const int* in_sizes, int n_in,
                              void* d_out, int out_size, void* d_ws, size_t ws_size,
                              hipStream_t stream) {
  const float* x   = (const float*)d_in[0];
  const float* bv  = (const float*)d_in[1];
  const int* cols  = (const int*)d_in[2];
  const int* rows  = (const int*)d_in[3];
  float* y = (float*)d_out;

  // ws layout: [wpk: 16,777,216 B][S: 33,882,112 B]  (needs ws >= 50.7 MB)
  bf16_t* wpk = (bf16_t*)d_ws;
  bf16_t* S   = (bf16_t*)((char*)d_ws + 16777216);

  prepack_kernel<<<dim3(128, 4), dim3(256), 0, stream>>>(bv, wpk);
  padzero_kernel<<<dim3(80), dim3(256), 0, stream>>>(S);
  xprep_kernel<<<dim3(32, 32, 4), dim3(256), 0, stream>>>(x, S);
  bsconv_kernel<<<dim3(8, 32, 4), dim3(256), 0, stream>>>(S, wpk, cols, rows, y);
}

// Round 5
// 185.469 us; speedup vs baseline: 1.4312x; 1.4312x over previous
//
#include <hip/hip_runtime.h>
#include <hip/hip_bf16.h>
#include <stdint.h>

typedef __bf16 bf16_t;
typedef bf16_t bf16x8 __attribute__((ext_vector_type(8)));
typedef float f32x4 __attribute__((ext_vector_type(4)));

#define T_LEN 2048
#define C_LEN 2048
#define NB 128
#define TN 256
#define SROWS 2064    // 16 zero-halo rows + 2048 data rows per batch
#define XROWS 320     // 5 x 8KB GLL rounds (512 thr); rows 0..271 consumed
#define SLAST 8271    // last valid S row (4*SROWS + 15, zeroed)

// async global->LDS, 16B per lane; LDS dest = wave-uniform base + lane*16
#define GLL(gp, lp) __builtin_amdgcn_global_load_lds( \
    (const __attribute__((address_space(1))) uint32_t*)(gp), \
    (__attribute__((address_space(3))) uint32_t*)(lp), 16, 0, 0)

// ---------------------------------------------------------------------------
// Prepack weights into per-lane MFMA A-fragment layout (verified r1/r2):
// wpk[blk][ks(32)][mt(4)][lane(64)][j(8)]
//   = bv[blk][o = mt*16 + (lane&15)][i = (ks&1)*32 + (lane>>4)*8 + j][k = ks>>1]
// ---------------------------------------------------------------------------
__global__ __launch_bounds__(256) void prepack_kernel(
    const float* __restrict__ bv, bf16_t* __restrict__ wpk)
{
  const int blk = blockIdx.x;
  const int mt  = blockIdx.y;
  const int tid = threadIdx.x;
  __shared__ float lw[16 * 64 * 17];

  const float* src = bv + (size_t)blk * 65536 + (size_t)mt * 16384;
  for (int p = 0; p < 16; ++p) {
    int idx = p * 1024 + tid * 4;
    const float4 v = *(const float4*)(src + idx);
    int o = idx >> 10;
    int i = (idx >> 4) & 63;
    int k = idx & 15;
    float* d = &lw[(o * 64 + i) * 17 + k];
    d[0] = v.x; d[1] = v.y; d[2] = v.z; d[3] = v.w;
  }
  __syncthreads();

  const int e0 = tid * 2;
  const int l  = e0 >> 3;
  const int j  = e0 & 7;
  const int o  = l & 15;
  for (int ks = 0; ks < 32; ++ks) {
    const int k  = ks >> 1;
    const int i0 = (ks & 1) * 32 + (l >> 4) * 8 + j;
    const float a = lw[(o * 64 + i0) * 17 + k];
    const float b = lw[(o * 64 + i0 + 1) * 17 + k];
    const uint16_t ba = __builtin_bit_cast(uint16_t, (bf16_t)a);
    const uint16_t bb = __builtin_bit_cast(uint16_t, (bf16_t)b);
    const uint32_t packed = (uint32_t)ba | ((uint32_t)bb << 16);
    const size_t off = ((((size_t)blk * 32 + ks) * 4 + mt) * 512) + e0;
    *(uint32_t*)(wpk + off) = packed;
  }
}

// ---------------------------------------------------------------------------
// Zero the halo rows of S.
// ---------------------------------------------------------------------------
__global__ __launch_bounds__(256) void padzero_kernel(bf16_t* __restrict__ S)
{
  const int p = blockIdx.x;  // 0..79
  const size_t g = (p < 64) ? ((size_t)(p >> 4) * SROWS + (p & 15))
                            : ((size_t)4 * SROWS + (p - 64));
  uint4 z = {0u, 0u, 0u, 0u};
  *(uint4*)(S + g * C_LEN + (size_t)threadIdx.x * 8) = z;
}

// ---------------------------------------------------------------------------
// x prepass: f32 [n][c][t] -> bf16 S[n][16+t][c'], c' = c ^ ((t&7)<<3)
// within each 64-ch block (XOR swizzle baked into global layout).
// ---------------------------------------------------------------------------
__global__ __launch_bounds__(256) void xprep_kernel(
    const float* __restrict__ x, bf16_t* __restrict__ S)
{
  const int tb = blockIdx.x, cb = blockIdx.y, n = blockIdx.z;
  const int tid = threadIdx.x;
  __shared__ float lt[64 * 67 + 4];

  #pragma unroll
  for (int p = 0; p < 4; ++p) {
    const int idx = p * 256 + tid;
    const int c   = idx >> 4;
    const int t4  = (idx & 15) * 4;
    const float4 v = *(const float4*)(
        x + ((size_t)n * C_LEN + cb * 64 + c) * T_LEN + tb * 64 + t4);
    float* d = &lt[c * 67 + t4];
    d[0] = v.x; d[1] = v.y; d[2] = v.z; d[3] = v.w;
  }
  __syncthreads();

  #pragma unroll
  for (int p = 0; p < 2; ++p) {
    const int idx = p * 256 + tid;
    const int tl  = idx >> 3;
    const int seg = idx & 7;
    const int t   = tb * 64 + tl;
    const int cbase = (seg * 8) ^ ((t & 7) << 3);
    uint32_t w[4];
    #pragma unroll
    for (int h = 0; h < 4; ++h) {
      const float a = lt[(cbase + 2 * h) * 67 + tl];
      const float b = lt[(cbase + 2 * h + 1) * 67 + tl];
      const uint16_t ba = __builtin_bit_cast(uint16_t, (bf16_t)a);
      const uint16_t bb = __builtin_bit_cast(uint16_t, (bf16_t)b);
      w[h] = (uint32_t)ba | ((uint32_t)bb << 16);
    }
    uint4 u4 = {w[0], w[1], w[2], w[3]};
    *(uint4*)(S + ((size_t)n * SROWS + 16 + t) * C_LEN + cb * 64 + seg * 8) = u4;
  }
}

// ---------------------------------------------------------------------------
// Main kernel, 512 threads (8 waves), 1 WG/CU, 148.5 KB LDS.
// Wave wv computes output rows [tr*64, +64) x t-cols [t0+wv*32, +32).
// All staging via global_load_lds (proven r2 pattern):
//  - W: 2 x 32KB chunk double-buffer (8 ks per chunk), 4 chunks/block.
//  - x: 2 x 40KB block double-buffer, issued 2 chunks ahead (at c==2).
// Counted vmcnt ledger (FIFO, uniform across waves), 2 raw barriers/chunk:
//  entry to (j,c=0): outstanding = [x(j):5, W(j,0):4] = 9.
//  c=0: +W(j,1):4  -> wait vmcnt(4)   [need x(j), W(j,0)]
//  c=1: +W(j,2):4  -> wait vmcnt(4)   [need W(j,1)]
//  c=2: +W(j,3):4, +x(j+1):5 -> wait vmcnt(9)  [need W(j,2)]  (tail: 4)
//  c=3: +W(j+1,0):4          -> wait vmcnt(9)  [need W(j,3)]  (tail: 0)
// ---------------------------------------------------------------------------
__global__ __launch_bounds__(512, 2) void bsconv_kernel(
    const bf16_t* __restrict__ S, const bf16_t* __restrict__ wpk,
    const int* __restrict__ cols, const int* __restrict__ rows,
    float* __restrict__ y)
{
  const int tt = blockIdx.x, tr = blockIdx.y, n = blockIdx.z;
  const int t0 = tt * TN;
  const int tid = threadIdx.x;
  const int lane = tid & 63, wv = tid >> 6;   // wv 0..7

  __shared__ __attribute__((aligned(16))) bf16_t xst[2][XROWS * 64];  // 81920 B
  __shared__ __attribute__((aligned(16))) bf16_t wlds[2][16384];      // 65536 B
  __shared__ int alist[NB];
  __shared__ int clds[NB];
  __shared__ unsigned long long wmask[2];

  // ---- build active-block list (order-preserving => deterministic) ----
  {
    const int r = (tid < NB) ? rows[tid] : -1;
    if (tid < NB) clds[tid] = cols[tid];
    const bool match = (r == tr);
    const unsigned long long m = __ballot(match);
    if (wv < 2 && lane == 0) wmask[wv] = m;
    __syncthreads();
    if (match) {
      int pos = __popcll(wmask[wv] & ((1ull << lane) - 1ull));
      if (wv == 1) pos += __popcll(wmask[0]);
      alist[pos] = tid;
    }
    __syncthreads();   // also drains all vmem: ledger starts at 0
  }
  const int cnt = __popcll(wmask[0]) + __popcll(wmask[1]);

  f32x4 acc[4][2];
  #pragma unroll
  for (int a = 0; a < 4; ++a)
    #pragma unroll
    for (int b = 0; b < 2; ++b) {
      f32x4 z = {0.f, 0.f, 0.f, 0.f};
      acc[a][b] = z;
    }

  const size_t srow0 = (size_t)n * SROWS + t0;  // S row of LDS row u=0
  const int lxb = tid * 16;                     // lane byte within an 8KB round

  auto issue_x = [&](int cb, int buf) {         // 5 rounds = 40KB
    #pragma unroll
    for (int q = 0; q < 5; ++q) {
      const int lb = q * 8192 + lxb;
      size_t gr = srow0 + (size_t)(lb >> 7);    // S row; rows>271 unused
      if (gr > (size_t)SLAST) gr = (size_t)SLAST;  // clamp (zero row)
      const int ib = (lb >> 1) & 63;
      GLL(S + gr * C_LEN + cb * 64 + ib, (char*)xst[buf] + lb);
    }
  };
  auto issue_w = [&](const bf16_t* wsrc, int buf) {  // 4 rounds = 32KB
    #pragma unroll
    for (int p = 0; p < 4; ++p) {
      const int lb = p * 8192 + lxb;
      GLL(wsrc + (lb >> 1), (char*)wlds[buf] + lb);
    }
  };

  if (cnt > 0) {
    issue_x(clds[alist[0]], 0);                       // x(0):5
    issue_w(wpk + (size_t)alist[0] * 65536, 0);       // W(0,0):4
  }

  for (int j = 0; j < cnt; ++j) {
    const bf16_t* wblk = wpk + (size_t)alist[j] * 65536;
    const bool havenext = (j + 1 < cnt);
    const int bnext = havenext ? alist[j + 1] : 0;
    const bf16_t* xb = xst[j & 1];

    #pragma unroll
    for (int c = 0; c < 4; ++c) {
      // ---- issues (program order defines the FIFO ledger) ----
      if (c < 3) {
        issue_w(wblk + (size_t)(c + 1) * 16384, (c + 1) & 1);
      } else if (havenext) {
        issue_w(wpk + (size_t)bnext * 65536, 0);      // next block chunk0
      }
      if (c == 2 && havenext) issue_x(clds[bnext], (j + 1) & 1);

      // ---- counted wait (see ledger above) ----
      if (c <= 1) {
        asm volatile("s_waitcnt vmcnt(4)" ::: "memory");
      } else if (havenext) {
        asm volatile("s_waitcnt vmcnt(9)" ::: "memory");
      } else if (c == 2) {
        asm volatile("s_waitcnt vmcnt(4)" ::: "memory");
      } else {
        asm volatile("s_waitcnt vmcnt(0)" ::: "memory");
      }
      __builtin_amdgcn_s_barrier();       // B_ready(c)
      __builtin_amdgcn_sched_barrier(0);

      const bf16_t* wl = wlds[c & 1];
      __builtin_amdgcn_s_setprio(1);
      #pragma unroll
      for (int ksl = 0; ksl < 8; ++ksl) {
        const int ks = c * 8 + ksl;
        const int k  = ks >> 1;               // conv tap
        const int ih = (ks & 1) * 32;         // channel half
        bf16x8 afr[4];
        #pragma unroll
        for (int mt = 0; mt < 4; ++mt)
          afr[mt] = *(const bf16x8*)(wl + ((ksl * 4 + mt) * 64 + lane) * 8);
        const int ub   = wv * 32 + (lane & 15) + k + 1;
        const int scol = (ih + ((lane >> 4) & 3) * 8) ^ ((ub & 7) << 3);
        bf16x8 bfr[2];
        #pragma unroll
        for (int nt = 0; nt < 2; ++nt)
          bfr[nt] = *(const bf16x8*)(xb + (ub + nt * 16) * 64 + scol);
        #pragma unroll
        for (int mt = 0; mt < 4; ++mt)
          #pragma unroll
          for (int nt = 0; nt < 2; ++nt)
            acc[mt][nt] = __builtin_amdgcn_mfma_f32_16x16x32_bf16(
                afr[mt], bfr[nt], acc[mt][nt], 0, 0, 0);
      }
      __builtin_amdgcn_s_setprio(0);
      __builtin_amdgcn_sched_barrier(0);
      __builtin_amdgcn_s_barrier();       // B_done(c): buffers reusable
    }
  }

  // ---- store (each output element exactly once; empty rows store zeros) ----
  const int mlo = ((lane >> 4) & 3) * 4, nn = lane & 15;
  #pragma unroll
  for (int mt = 0; mt < 4; ++mt) {
    #pragma unroll
    for (int nt = 0; nt < 2; ++nt) {
      const int t = t0 + wv * 32 + nt * 16 + nn;
      float* yp = y + ((size_t)n * C_LEN + (size_t)(tr * 64 + mt * 16 + mlo)) * T_LEN + t;
      #pragma unroll
      for (int r = 0; r < 4; ++r)
        yp[(size_t)r * T_LEN] = acc[mt][nt][r];
    }
  }
}

extern "C" void kernel_launch(void* const* d_in, const int* in_sizes, int n_in,
                              void* d_out, int out_size, void* d_ws, size_t ws_size,
                              hipStream_t stream) {
  const float* x   = (const float*)d_in[0];
  const float* bv  = (const float*)d_in[1];
  const int* cols  = (const int*)d_in[2];
  const int* rows  = (const int*)d_in[3];
  float* y = (float*)d_out;

  // ws layout: [wpk: 16,777,216 B][S: 33,882,112 B]  (needs ws >= 50.7 MB)
  bf16_t* wpk = (bf16_t*)d_ws;
  bf16_t* S   = (bf16_t*)((char*)d_ws + 16777216);

  prepack_kernel<<<dim3(128, 4), dim3(256), 0, stream>>>(bv, wpk);
  padzero_kernel<<<dim3(80), dim3(256), 0, stream>>>(S);
  xprep_kernel<<<dim3(32, 32, 4), dim3(256), 0, stream>>>(x, S);
  bsconv_kernel<<<dim3(8, 32, 4), dim3(512), 0, stream>>>(S, wpk, cols, rows, y);
}

// Round 6
// 175.658 us; speedup vs baseline: 1.5111x; 1.0559x over previous
//
#include <hip/hip_runtime.h>
#include <hip/hip_bf16.h>
#include <stdint.h>

typedef __bf16 bf16_t;
typedef bf16_t bf16x8 __attribute__((ext_vector_type(8)));
typedef float f32x4 __attribute__((ext_vector_type(4)));

#define T_LEN 2048
#define C_LEN 2048
#define NB 128
#define TN 256
#define SROWS 2064    // 16 zero-halo rows + 2048 data rows per batch
#define XROWS 288     // 9 x 4KB GLL rounds (256 thr); rows 0..271 consumed

// async global->LDS, 16B per lane; LDS dest = wave-uniform base + lane*16
#define GLL(gp, lp) __builtin_amdgcn_global_load_lds( \
    (const __attribute__((address_space(1))) uint32_t*)(gp), \
    (__attribute__((address_space(3))) uint32_t*)(lp), 16, 0, 0)

// ---------------------------------------------------------------------------
// Prepack weights into per-lane MFMA A-fragment layout (verified r1-r5):
// wpk[blk][ks(32)][mt(4)][lane(64)][j(8)]
//   = bv[blk][o = mt*16 + (lane&15)][i = (ks&1)*32 + (lane>>4)*8 + j][k = ks>>1]
// ---------------------------------------------------------------------------
__global__ __launch_bounds__(256) void prepack_kernel(
    const float* __restrict__ bv, bf16_t* __restrict__ wpk)
{
  const int blk = blockIdx.x;
  const int mt  = blockIdx.y;
  const int tid = threadIdx.x;
  __shared__ float lw[16 * 64 * 17];

  const float* src = bv + (size_t)blk * 65536 + (size_t)mt * 16384;
  for (int p = 0; p < 16; ++p) {
    int idx = p * 1024 + tid * 4;
    const float4 v = *(const float4*)(src + idx);
    int o = idx >> 10;
    int i = (idx >> 4) & 63;
    int k = idx & 15;
    float* d = &lw[(o * 64 + i) * 17 + k];
    d[0] = v.x; d[1] = v.y; d[2] = v.z; d[3] = v.w;
  }
  __syncthreads();

  const int e0 = tid * 2;
  const int l  = e0 >> 3;
  const int j  = e0 & 7;
  const int o  = l & 15;
  for (int ks = 0; ks < 32; ++ks) {
    const int k  = ks >> 1;
    const int i0 = (ks & 1) * 32 + (l >> 4) * 8 + j;
    const float a = lw[(o * 64 + i0) * 17 + k];
    const float b = lw[(o * 64 + i0 + 1) * 17 + k];
    const uint16_t ba = __builtin_bit_cast(uint16_t, (bf16_t)a);
    const uint16_t bb = __builtin_bit_cast(uint16_t, (bf16_t)b);
    const uint32_t packed = (uint32_t)ba | ((uint32_t)bb << 16);
    const size_t off = ((((size_t)blk * 32 + ks) * 4 + mt) * 512) + e0;
    *(uint32_t*)(wpk + off) = packed;
  }
}

// ---------------------------------------------------------------------------
// Zero the halo rows of S.
// ---------------------------------------------------------------------------
__global__ __launch_bounds__(256) void padzero_kernel(bf16_t* __restrict__ S)
{
  const int p = blockIdx.x;  // 0..79
  const size_t g = (p < 64) ? ((size_t)(p >> 4) * SROWS + (p & 15))
                            : ((size_t)4 * SROWS + (p - 64));
  uint4 z = {0u, 0u, 0u, 0u};
  *(uint4*)(S + g * C_LEN + (size_t)threadIdx.x * 8) = z;
}

// ---------------------------------------------------------------------------
// x prepass: f32 [n][c][t] -> bf16 S[n][16+t][c'], c' = c ^ ((t&7)<<3)
// within each 64-ch block (XOR swizzle baked into global layout).
// ---------------------------------------------------------------------------
__global__ __launch_bounds__(256) void xprep_kernel(
    const float* __restrict__ x, bf16_t* __restrict__ S)
{
  const int tb = blockIdx.x, cb = blockIdx.y, n = blockIdx.z;
  const int tid = threadIdx.x;
  __shared__ float lt[64 * 67 + 4];

  #pragma unroll
  for (int p = 0; p < 4; ++p) {
    const int idx = p * 256 + tid;
    const int c   = idx >> 4;
    const int t4  = (idx & 15) * 4;
    const float4 v = *(const float4*)(
        x + ((size_t)n * C_LEN + cb * 64 + c) * T_LEN + tb * 64 + t4);
    float* d = &lt[c * 67 + t4];
    d[0] = v.x; d[1] = v.y; d[2] = v.z; d[3] = v.w;
  }
  __syncthreads();

  #pragma unroll
  for (int p = 0; p < 2; ++p) {
    const int idx = p * 256 + tid;
    const int tl  = idx >> 3;
    const int seg = idx & 7;
    const int t   = tb * 64 + tl;
    const int cbase = (seg * 8) ^ ((t & 7) << 3);
    uint32_t w[4];
    #pragma unroll
    for (int h = 0; h < 4; ++h) {
      const float a = lt[(cbase + 2 * h) * 67 + tl];
      const float b = lt[(cbase + 2 * h + 1) * 67 + tl];
      const uint16_t ba = __builtin_bit_cast(uint16_t, (bf16_t)a);
      const uint16_t bb = __builtin_bit_cast(uint16_t, (bf16_t)b);
      w[h] = (uint32_t)ba | ((uint32_t)bb << 16);
    }
    uint4 u4 = {w[0], w[1], w[2], w[3]};
    *(uint4*)(S + ((size_t)n * SROWS + 16 + t) * C_LEN + cb * 64 + seg * 8) = u4;
  }
}

// ---------------------------------------------------------------------------
// Main kernel: 256 thr (4 waves), 2 WG/CU, ~71 KB LDS.
// Wave wv: output rows [tr*64,+64) x t-cols [t0+wv*64,+64)  (mt=4, nt=4 --
// the 64x64 wave tile minimizes LDS bytes/MFMA: 512 B vs r5's 768 B).
// - x: SINGLE buffer (9x4KB GLL at block top); sibling WG (2/CU) covers
//   the staging stall via TLP.
// - W: 2x16KB chunk double-buffer (4 ks/chunk, 8 chunks/block), GLL.
// Counted vmcnt ledger (GLL-only, uniform across waves, FIFO-verified):
//  steady entry at block top: [W(j,0):4] -> issue x(j):9 -> c-loop:
//  c<7: issue W(j,c+1):4, wait vmcnt(4)   (x+older W landed)
//  c=7: issue W(j+1,0):4,  wait vmcnt(4)  (last block: wait vmcnt(0))
// ---------------------------------------------------------------------------
__global__ __launch_bounds__(256, 2) void bsconv_kernel(
    const bf16_t* __restrict__ S, const bf16_t* __restrict__ wpk,
    const int* __restrict__ cols, const int* __restrict__ rows,
    float* __restrict__ y)
{
  const int tt = blockIdx.x, tr = blockIdx.y, n = blockIdx.z;
  const int t0 = tt * TN;
  const int tid = threadIdx.x;
  const int lane = tid & 63, wv = tid >> 6;   // wv 0..3

  __shared__ __attribute__((aligned(16))) bf16_t xst[XROWS * 64];  // 36864 B
  __shared__ __attribute__((aligned(16))) bf16_t wlds[2][8192];    // 32768 B
  __shared__ int alist[NB];
  __shared__ int clds[NB];
  __shared__ unsigned long long wmask[2];

  // ---- build active-block list (order-preserving => deterministic) ----
  {
    const int r = (tid < NB) ? rows[tid] : -1;
    if (tid < NB) clds[tid] = cols[tid];
    const bool match = (r == tr);
    const unsigned long long m = __ballot(match);
    if (wv < 2 && lane == 0) wmask[wv] = m;
    __syncthreads();
    if (match) {
      int pos = __popcll(wmask[wv] & ((1ull << lane) - 1ull));
      if (wv == 1) pos += __popcll(wmask[0]);
      alist[pos] = tid;
    }
    __syncthreads();   // also drains all vmem: ledger starts at 0
  }
  const int cnt = __popcll(wmask[0]) + __popcll(wmask[1]);

  f32x4 acc[4][4];
  #pragma unroll
  for (int a = 0; a < 4; ++a)
    #pragma unroll
    for (int b = 0; b < 4; ++b) {
      f32x4 z = {0.f, 0.f, 0.f, 0.f};
      acc[a][b] = z;
    }

  const size_t srow0 = (size_t)n * SROWS + t0;  // S row of LDS row u=0
  const int lxb = tid * 16;                     // lane byte within a 4KB round

  auto issue_x = [&](int cb) {                  // 9 rounds = 36 KB, single buf
    #pragma unroll
    for (int q = 0; q < 9; ++q) {
      const int lb = q * 4096 + lxb;
      const int u  = lb >> 7;                   // LDS row (128 B rows)
      const int ib = (lb >> 1) & 63;
      GLL(S + (srow0 + u) * C_LEN + cb * 64 + ib, (char*)xst + lb);
    }
  };
  auto issue_w = [&](const bf16_t* wsrc, int buf) {  // 4 rounds = 16KB
    #pragma unroll
    for (int p = 0; p < 4; ++p) {
      const int lb = p * 4096 + lxb;
      GLL(wsrc + (lb >> 1), (char*)wlds[buf] + lb);
    }
  };

  if (cnt > 0) {
    issue_x(clds[alist[0]]);                          // x(0):9
    issue_w(wpk + (size_t)alist[0] * 65536, 0);       // W(0,0):4
  }

  for (int j = 0; j < cnt; ++j) {
    const bf16_t* wblk = wpk + (size_t)alist[j] * 65536;
    const bool havenext = (j + 1 < cnt);
    const int bnext = havenext ? alist[j + 1] : 0;

    #pragma unroll
    for (int c = 0; c < 8; ++c) {
      // ---- issues (program order = FIFO ledger) ----
      if (c < 7) {
        issue_w(wblk + (size_t)(c + 1) * 8192, (c + 1) & 1);
      } else if (havenext) {
        issue_w(wpk + (size_t)bnext * 65536, 0);      // next block chunk0
      }

      // ---- counted wait ----
      if (c < 7 || havenext) {
        asm volatile("s_waitcnt vmcnt(4)" ::: "memory");
      } else {
        asm volatile("s_waitcnt vmcnt(0)" ::: "memory");
      }
      __builtin_amdgcn_s_barrier();       // B_ready(c)
      __builtin_amdgcn_sched_barrier(0);

      const bf16_t* wl = wlds[c & 1];
      __builtin_amdgcn_s_setprio(1);
      #pragma unroll
      for (int ksl = 0; ksl < 4; ++ksl) {
        const int ks = c * 4 + ksl;
        const int k  = ks >> 1;               // conv tap
        const int ih = (ks & 1) * 32;         // channel half
        bf16x8 afr[4];
        #pragma unroll
        for (int mt = 0; mt < 4; ++mt)
          afr[mt] = *(const bf16x8*)(wl + ((ksl * 4 + mt) * 64 + lane) * 8);
        const int ub   = wv * 64 + (lane & 15) + k + 1;
        const int scol = (ih + ((lane >> 4) & 3) * 8) ^ ((ub & 7) << 3);
        bf16x8 bfr[4];
        #pragma unroll
        for (int nt = 0; nt < 4; ++nt)
          bfr[nt] = *(const bf16x8*)(xst + (ub + nt * 16) * 64 + scol);
        #pragma unroll
        for (int mt = 0; mt < 4; ++mt)
          #pragma unroll
          for (int nt = 0; nt < 4; ++nt)
            acc[mt][nt] = __builtin_amdgcn_mfma_f32_16x16x32_bf16(
                afr[mt], bfr[nt], acc[mt][nt], 0, 0, 0);
      }
      __builtin_amdgcn_s_setprio(0);
      __builtin_amdgcn_sched_barrier(0);
      __builtin_amdgcn_s_barrier();       // B_done(c): buffers reusable
    }

    // next block's x into the single buffer: all waves are past c=7's
    // trailing barrier (done reading xst), so the overwrite is safe.
    if (havenext) issue_x(clds[bnext]);
  }

  // ---- store (each output element exactly once; empty rows store zeros) ----
  const int mlo = ((lane >> 4) & 3) * 4, nn = lane & 15;
  #pragma unroll
  for (int mt = 0; mt < 4; ++mt) {
    #pragma unroll
    for (int nt = 0; nt < 4; ++nt) {
      const int t = t0 + wv * 64 + nt * 16 + nn;
      float* yp = y + ((size_t)n * C_LEN + (size_t)(tr * 64 + mt * 16 + mlo)) * T_LEN + t;
      #pragma unroll
      for (int r = 0; r < 4; ++r)
        yp[(size_t)r * T_LEN] = acc[mt][nt][r];
    }
  }
}

extern "C" void kernel_launch(void* const* d_in, const int* in_sizes, int n_in,
                              void* d_out, int out_size, void* d_ws, size_t ws_size,
                              hipStream_t stream) {
  const float* x   = (const float*)d_in[0];
  const float* bv  = (const float*)d_in[1];
  const int* cols  = (const int*)d_in[2];
  const int* rows  = (const int*)d_in[3];
  float* y = (float*)d_out;

  // ws layout: [wpk: 16,777,216 B][S: 33,882,112 B]  (needs ws >= 50.7 MB)
  bf16_t* wpk = (bf16_t*)d_ws;
  bf16_t* S   = (bf16_t*)((char*)d_ws + 16777216);

  prepack_kernel<<<dim3(128, 4), dim3(256), 0, stream>>>(bv, wpk);
  padzero_kernel<<<dim3(80), dim3(256), 0, stream>>>(S);
  xprep_kernel<<<dim3(32, 32, 4), dim3(256), 0, stream>>>(x, S);
  bsconv_kernel<<<dim3(8, 32, 4), dim3(256), 0, stream>>>(S, wpk, cols, rows, y);
}